// Round 5
// baseline (350.014 us; speedup 1.0000x reference)
//
#include <hip/hip_runtime.h>

#define B_ 16
#define N_ 16384
#define S_ 4096
#define K_ 16
#define TS 32
#define DOUT 128

typedef __bf16 bf16;
typedef __attribute__((ext_vector_type(8))) __bf16 bf16x8;
typedef __attribute__((ext_vector_type(4))) float f32x4;

__device__ __forceinline__ float lo_bf(unsigned u) {
  union { unsigned i; float f; } c; c.i = u << 16; return c.f;
}
__device__ __forceinline__ float hi_bf(unsigned u) {
  union { unsigned i; float f; } c; c.i = u & 0xffff0000u; return c.f;
}
__device__ __forceinline__ unsigned pack2(float a, float b) {
  unsigned short ua = __builtin_bit_cast(unsigned short, (bf16)a);
  unsigned short ub = __builtin_bit_cast(unsigned short, (bf16)b);
  return (unsigned)ua | ((unsigned)ub << 16);
}
__device__ __forceinline__ void unpack8(uint4 q, float* o) {
  o[0] = lo_bf(q.x); o[1] = hi_bf(q.x);
  o[2] = lo_bf(q.y); o[3] = hi_bf(q.y);
  o[4] = lo_bf(q.z); o[5] = hi_bf(q.z);
  o[6] = lo_bf(q.w); o[7] = hi_bf(q.w);
}

template <int NCH>
__device__ __forceinline__ void ln_leaky(const float* h, const float* g, const float* e, float* o) {
  float m = 0.f;
#pragma unroll
  for (int j = 0; j < NCH; ++j) m += h[j];
  m *= (1.0f / NCH);
  float v = 0.f;
#pragma unroll
  for (int j = 0; j < NCH; ++j) { float d = h[j] - m; v += d * d; }
  v *= (1.0f / NCH);
  float inv = rsqrtf(v + 1e-5f);
#pragma unroll
  for (int j = 0; j < NCH; ++j) {
    float t = (h[j] - m) * inv * g[j] + e[j];
    o[j] = t < 0.f ? 0.2f * t : t;
  }
}

// Diagnostic: encode a hip launch error into the output (absmax ~= code).
__global__ void k_fill(float* out, float v) {
  out[blockIdx.x * 256 + threadIdx.x] = v;
}

// points [B,64,N] f32 -> points_t [B,N,64] bf16 (contiguous per-point gathers).
__global__ void k_transpose(const float* __restrict__ pts, bf16* __restrict__ pt) {
  int b = blockIdx.y;
  int n = blockIdx.x * 256 + threadIdx.x;
  const float* src = pts + (size_t)b * 64 * N_ + n;
  unsigned wbuf[32];
#pragma unroll
  for (int c = 0; c < 32; ++c)
    wbuf[c] = pack2(src[(size_t)(2 * c) * N_], src[(size_t)(2 * c + 1) * N_]);
  uint4* dst = (uint4*)(pt + ((size_t)b * N_ + n) * 64);
#pragma unroll
  for (int i = 0; i < 8; ++i)
    dst[i] = make_uint4(wbuf[4 * i], wbuf[4 * i + 1], wbuf[4 * i + 2], wbuf[4 * i + 3]);
}

// wl [1072,128] f32 -> wl_t [128,1088] bf16 with rows 1072..1087 zeroed.
__global__ void k_wlt(const float* __restrict__ wl, bf16* __restrict__ wlt) {
  int j = blockIdx.x;  // 0..127 (output column)
  for (int r = threadIdx.x; r < 1088; r += 256) {
    bf16 v = (bf16)0.0f;
    if (r < 1072) v = (bf16)wl[(size_t)r * 128 + j];
    wlt[(size_t)j * 1088 + r] = v;
  }
}

__global__ __launch_bounds__(256) void k_main(
    const float* __restrict__ xyz, const float* __restrict__ nxyz,
    const int* __restrict__ nnidx,
    const float* __restrict__ pts, const float* __restrict__ wl,
    const bf16* __restrict__ ptT, const bf16* __restrict__ wlT,
    const float* __restrict__ w0p, const float* __restrict__ b0p,
    const float* __restrict__ g0p, const float* __restrict__ be0p,
    const float* __restrict__ w1p, const float* __restrict__ b1p,
    const float* __restrict__ g1p, const float* __restrict__ be1p,
    const float* __restrict__ w2p, const float* __restrict__ b2p,
    const float* __restrict__ g2p, const float* __restrict__ be2p,
    const float* __restrict__ blp, const float* __restrict__ glp,
    const float* __restrict__ belp, float* __restrict__ out, int use_ws) {
  __shared__ float nx[3][TS];
  __shared__ int idxs[TS * K_];
  // w_s bf16[32][264] (16896B) aliased by out_s float[32][128] (16384B) in epilogue
  __shared__ __align__(16) unsigned char poolB[TS * 264 * 2];
  __shared__ __align__(16) bf16 gxn_s[TS][K_][4];
  __shared__ __align__(16) bf16 feat_s[TS][136];   // [s][k*8+c], +8 pad per row
  __shared__ __align__(16) bf16 aggA[TS][136];     // [s][c*16+m], +8 pad
  __shared__ __align__(16) bf16 wlB[64][136];      // [n_local][k_local], +8 pad
  __shared__ float ln_m[TS], ln_i[TS];

  const int tid = threadIdx.x;
  const int b = blockIdx.y;
  const int s0 = blockIdx.x * TS;
  bf16* w_s = (bf16*)poolB;  // [s*264 + k*16 + m]

  // ---- phase 0: idx + new_xyz tile ----
  if (tid < 96) {
    int c = tid >> 5, j = tid & 31;
    nx[c][j] = nxyz[((size_t)b * 3 + c) * S_ + s0 + j];
  }
  {
    size_t base = ((size_t)b * S_ + s0) * K_;
    idxs[tid] = nnidx[base + tid];
    idxs[tid + 256] = nnidx[base + tid + 256];
  }
  __syncthreads();

  // ---- phase 1: WeightNet, 2 neighbors per thread, weights in registers ----
  {
    int p0 = tid * 2;
    int s = p0 >> 4;
    int k0 = p0 & 15;
    int na = idxs[p0], nb2 = idxs[p0 + 1];
    float xa[3], xb[3];
#pragma unroll
    for (int c = 0; c < 3; ++c) {
      float nv = nx[c][s];
      xa[c] = xyz[((size_t)b * 3 + c) * N_ + na] - nv;
      xb[c] = xyz[((size_t)b * 3 + c) * N_ + nb2] - nv;
    }
    float ya[8], yb[8];
    {  // layer 0: 3 -> 8
      float h0[8], h1[8];
#pragma unroll
      for (int j = 0; j < 8; ++j) {
        h0[j] = b0p[j] + xa[0] * w0p[j] + xa[1] * w0p[8 + j] + xa[2] * w0p[16 + j];
        h1[j] = b0p[j] + xb[0] * w0p[j] + xb[1] * w0p[8 + j] + xb[2] * w0p[16 + j];
      }
      ln_leaky<8>(h0, g0p, be0p, ya);
      ln_leaky<8>(h1, g0p, be0p, yb);
    }
    {  // layer 1: 8 -> 8
      float h0[8], h1[8];
#pragma unroll
      for (int j = 0; j < 8; ++j) { h0[j] = b1p[j]; h1[j] = b1p[j]; }
#pragma unroll
      for (int i = 0; i < 8; ++i) {
#pragma unroll
        for (int j = 0; j < 8; ++j) {
          float w = w1p[i * 8 + j];
          h0[j] += ya[i] * w; h1[j] += yb[i] * w;
        }
      }
      ln_leaky<8>(h0, g1p, be1p, ya);
      ln_leaky<8>(h1, g1p, be1p, yb);
    }
    {  // layer 2: 8 -> 16
      float h0[16], h1[16];
#pragma unroll
      for (int j = 0; j < 16; ++j) { h0[j] = b2p[j]; h1[j] = b2p[j]; }
#pragma unroll
      for (int i = 0; i < 8; ++i) {
#pragma unroll
        for (int j = 0; j < 16; ++j) {
          float w = w2p[i * 16 + j];
          h0[j] += ya[i] * w; h1[j] += yb[i] * w;
        }
      }
      float z0[16], z1[16];
      ln_leaky<16>(h0, g2p, be2p, z0);
      ln_leaky<16>(h1, g2p, be2p, z1);
      bf16* r0 = w_s + s * 264 + k0 * 16;
      bf16* r1 = r0 + 16;
#pragma unroll
      for (int j = 0; j < 16; j += 2) {
        *(unsigned*)(r0 + j) = pack2(z0[j], z0[j + 1]);
        *(unsigned*)(r1 + j) = pack2(z1[j], z1[j + 1]);
      }
    }
    *(unsigned*)&gxn_s[s][k0][0] = pack2(xa[0], xa[1]);
    *(unsigned*)&gxn_s[s][k0][2] = pack2(xa[2], 0.0f);
    *(unsigned*)&gxn_s[s][k0 + 1][0] = pack2(xb[0], xb[1]);
    *(unsigned*)&gxn_s[s][k0 + 1][2] = pack2(xb[2], 0.0f);
  }

  // ---- MFMA setup ----
  const int lane = tid & 63;
  const int wv = tid >> 6;
  const int rt = wv & 1;   // row tile: s rows 16*rt..16*rt+15
  const int cw = wv >> 1;  // col-tile pair within half
  const int quad = lane >> 4;
  const int l16 = lane & 15;
  f32x4 a00 = {0.f, 0.f, 0.f, 0.f};
  f32x4 a01 = a00, a10 = a00, a11 = a00;

  const bf16* ptB = ptT + (size_t)b * N_ * 64;

  for (int ch = 0; ch < 9; ++ch) {
    const int kw = (ch < 8) ? 128 : 64;
    __syncthreads();  // prev MFMA done with wlB/aggA; prev agg done with feat_s
    // build feat_s for this chunk
    if (ch < 8) {
#pragma unroll
      for (int pp = 0; pp < 2; ++pp) {
        int p = tid + pp * 256;
        int s = p >> 4, k = p & 15;
        int n = idxs[p];
        if (use_ws) {
          uint4 v = *(const uint4*)(ptB + (size_t)n * 64 + ch * 8);
          *(uint4*)&feat_s[s][k * 8] = v;
        } else {
          const float* base = pts + ((size_t)b * 64 + ch * 8) * N_ + n;
          unsigned u[4];
#pragma unroll
          for (int c = 0; c < 4; ++c)
            u[c] = pack2(base[(size_t)(2 * c) * N_], base[(size_t)(2 * c + 1) * N_]);
          *(uint4*)&feat_s[s][k * 8] = make_uint4(u[0], u[1], u[2], u[3]);
        }
      }
    } else {
#pragma unroll
      for (int pp = 0; pp < 2; ++pp) {
        int p = tid + pp * 256;
        int s = p >> 4, k = p & 15;
        uint4 v;
        v.x = *(const unsigned*)&gxn_s[s][k][0];
        v.y = *(const unsigned*)&gxn_s[s][k][2];
        v.z = 0u; v.w = 0u;
        *(uint4*)&feat_s[s][k * 8] = v;
      }
    }
    // stage wl chunk, half 0 (output cols 0..63)
    if (use_ws) {
      int j = tid >> 2, seg = tid & 3;
      int per = kw >> 2;
      const bf16* src = wlT + (size_t)j * 1088 + ch * 128 + seg * per;
      bf16* dst = &wlB[j][seg * per];
#pragma unroll
      for (int i = 0; i < 32; i += 8)
        if (i < per) *(uint4*)(dst + i) = *(const uint4*)(src + i);
    } else {
      for (int o = tid; o < 64 * kw; o += 256) {
        int nl = o & 63, kl = o >> 6;
        int row = ch * 128 + kl;
        wlB[nl][kl] = (row < 1072) ? (bf16)wl[(size_t)row * 128 + nl] : (bf16)0.0f;
      }
    }
    __syncthreads();
    // agg: aggA[s][c*16+m] = sum_k feat[s,k,c] * w[s,k,m]
    {
      int s = tid >> 3, mp = tid & 7;  // m = 2*mp, 2*mp+1
      float acc0[8], acc1[8];
#pragma unroll
      for (int c = 0; c < 8; ++c) { acc0[c] = 0.f; acc1[c] = 0.f; }
      const bf16* wrow = w_s + s * 264 + 2 * mp;
      const bf16* frow = &feat_s[s][0];
#pragma unroll
      for (int k = 0; k < 16; ++k) {
        unsigned wp = *(const unsigned*)(wrow + k * 16);
        float wf0 = lo_bf(wp), wf1 = hi_bf(wp);
        float f[8];
        unpack8(*(const uint4*)(frow + k * 8), f);
#pragma unroll
        for (int c = 0; c < 8; ++c) { acc0[c] += f[c] * wf0; acc1[c] += f[c] * wf1; }
      }
      bf16* arow = &aggA[s][0];
#pragma unroll
      for (int c = 0; c < 8; ++c)
        *(unsigned*)(arow + c * 16 + 2 * mp) = pack2(acc0[c], acc1[c]);
    }
    __syncthreads();
    // MFMA half 0
    {
      const int nkk = kw >> 5;
      const bf16* arow = &aggA[rt * 16 + l16][quad * 8];
      const bf16* b0r = &wlB[(2 * cw + 0) * 16 + l16][quad * 8];
      const bf16* b1r = &wlB[(2 * cw + 1) * 16 + l16][quad * 8];
      for (int kk = 0; kk < nkk; ++kk) {
        bf16x8 af = *(const bf16x8*)(arow + kk * 32);
        bf16x8 bf0 = *(const bf16x8*)(b0r + kk * 32);
        bf16x8 bf1 = *(const bf16x8*)(b1r + kk * 32);
        a00 = __builtin_amdgcn_mfma_f32_16x16x32_bf16(af, bf0, a00, 0, 0, 0);
        a01 = __builtin_amdgcn_mfma_f32_16x16x32_bf16(af, bf1, a01, 0, 0, 0);
      }
    }
    __syncthreads();
    // stage wl chunk, half 1 (output cols 64..127)
    if (use_ws) {
      int j = tid >> 2, seg = tid & 3;
      int per = kw >> 2;
      const bf16* src = wlT + (size_t)(64 + j) * 1088 + ch * 128 + seg * per;
      bf16* dst = &wlB[j][seg * per];
#pragma unroll
      for (int i = 0; i < 32; i += 8)
        if (i < per) *(uint4*)(dst + i) = *(const uint4*)(src + i);
    } else {
      for (int o = tid; o < 64 * kw; o += 256) {
        int nl = o & 63, kl = o >> 6;
        int row = ch * 128 + kl;
        wlB[nl][kl] = (row < 1072) ? (bf16)wl[(size_t)row * 128 + 64 + nl] : (bf16)0.0f;
      }
    }
    __syncthreads();
    // MFMA half 1
    {
      const int nkk = kw >> 5;
      const bf16* arow = &aggA[rt * 16 + l16][quad * 8];
      const bf16* b0r = &wlB[(2 * cw + 0) * 16 + l16][quad * 8];
      const bf16* b1r = &wlB[(2 * cw + 1) * 16 + l16][quad * 8];
      for (int kk = 0; kk < nkk; ++kk) {
        bf16x8 af = *(const bf16x8*)(arow + kk * 32);
        bf16x8 bf0 = *(const bf16x8*)(b0r + kk * 32);
        bf16x8 bf1 = *(const bf16x8*)(b1r + kk * 32);
        a10 = __builtin_amdgcn_mfma_f32_16x16x32_bf16(af, bf0, a10, 0, 0, 0);
        a11 = __builtin_amdgcn_mfma_f32_16x16x32_bf16(af, bf1, a11, 0, 0, 0);
      }
    }
  }

  __syncthreads();
  // ---- epilogue: +bl, LN over 128, *gl+bel, leaky, transposed f32 store ----
  float* out_s = (float*)poolB;  // [32][128], aliases w_s (dead now)
  {
    int row = rt * 16 + quad * 4;
    int c0 = (2 * cw + 0) * 16 + l16;
    int c1 = (2 * cw + 1) * 16 + l16;
    int c2 = 64 + c0;
    int c3 = 64 + c1;
    float bl0 = blp[c0], bl1 = blp[c1], bl2 = blp[c2], bl3 = blp[c3];
#pragma unroll
    for (int r = 0; r < 4; ++r) {
      out_s[(row + r) * 128 + c0] = a00[r] + bl0;
      out_s[(row + r) * 128 + c1] = a01[r] + bl1;
      out_s[(row + r) * 128 + c2] = a10[r] + bl2;
      out_s[(row + r) * 128 + c3] = a11[r] + bl3;
    }
  }
  __syncthreads();
  if (tid < TS) {
    const float* rowp = out_s + tid * 128;
    float m = 0.f;
#pragma unroll 16
    for (int d2 = 0; d2 < 128; ++d2) m += rowp[d2];
    m *= (1.0f / 128.0f);
    float v = 0.f;
#pragma unroll 16
    for (int d2 = 0; d2 < 128; ++d2) { float dd = rowp[d2] - m; v += dd * dd; }
    v *= (1.0f / 128.0f);
    ln_m[tid] = m;
    ln_i[tid] = rsqrtf(v + 1e-5f);
  }
  __syncthreads();
  {
    int d = tid >> 1, sh = tid & 1;
    float gld = glp[d], beld = belp[d];
    float vals[16];
#pragma unroll
    for (int j = 0; j < 16; ++j) {
      int r = sh * 16 + j;
      float v = (out_s[r * 128 + d] - ln_m[r]) * ln_i[r] * gld + beld;
      vals[j] = v < 0.f ? 0.2f * v : v;
    }
    float* op = out + ((size_t)b * DOUT + d) * S_ + s0 + sh * 16;
#pragma unroll
    for (int i = 0; i < 4; ++i)
      *(float4*)(op + 4 * i) =
          make_float4(vals[4 * i], vals[4 * i + 1], vals[4 * i + 2], vals[4 * i + 3]);
  }
}

extern "C" void kernel_launch(void* const* d_in, const int* in_sizes, int n_in,
                              void* d_out, int out_size, void* d_ws, size_t ws_size,
                              hipStream_t stream) {
  const float* xyz  = (const float*)d_in[0];
  const float* pts  = (const float*)d_in[1];
  const float* nxyz = (const float*)d_in[2];
  const int* nnidx  = (const int*)d_in[3];
  const float* w0p  = (const float*)d_in[4];
  const float* b0p  = (const float*)d_in[5];
  const float* g0p  = (const float*)d_in[6];
  const float* be0p = (const float*)d_in[7];
  const float* w1p  = (const float*)d_in[8];
  const float* b1p  = (const float*)d_in[9];
  const float* g1p  = (const float*)d_in[10];
  const float* be1p = (const float*)d_in[11];
  const float* w2p  = (const float*)d_in[12];
  const float* b2p  = (const float*)d_in[13];
  const float* g2p  = (const float*)d_in[14];
  const float* be2p = (const float*)d_in[15];
  const float* wlp  = (const float*)d_in[16];
  const float* blp  = (const float*)d_in[17];
  const float* glp  = (const float*)d_in[18];
  const float* belp = (const float*)d_in[19];
  float* out = (float*)d_out;

  const size_t PTT_BYTES = (size_t)B_ * N_ * 64 * 2;   // 33.55 MB
  const size_t WLT_BYTES = (size_t)128 * 1088 * 2;     // 0.27 MB
  const int use_ws = (ws_size >= PTT_BYTES + WLT_BYTES) ? 1 : 0;
  bf16* ptT = (bf16*)d_ws;
  bf16* wlT = (bf16*)((char*)d_ws + PTT_BYTES);

  (void)hipGetLastError();  // clear stale error state

  hipError_t e1 = hipSuccess, e2 = hipSuccess;
  if (use_ws) {
    k_transpose<<<dim3(N_ / 256, B_), dim3(256), 0, stream>>>(pts, ptT);
    e1 = hipGetLastError();
    k_wlt<<<dim3(128), dim3(256), 0, stream>>>(wlp, wlT);
    e2 = hipGetLastError();
  }
  k_main<<<dim3(S_ / TS, B_), dim3(256), 0, stream>>>(
      xyz, nxyz, nnidx, pts, wlp, ptT, wlT,
      w0p, b0p, g0p, be0p, w1p, b1p, g1p, be1p,
      w2p, b2p, g2p, be2p, blp, glp, belp, out, use_ws);
  hipError_t e3 = hipGetLastError();

  // Diagnostic channel: encode launch failures as absmax magnitudes.
  if (e1 != hipSuccess)
    k_fill<<<dim3(8), dim3(256), 0, stream>>>(out, 2000.0f + (float)(int)e1);
  if (e2 != hipSuccess)
    k_fill<<<dim3(8), dim3(256), 0, stream>>>(out, 3000.0f + (float)(int)e2);
  if (e3 != hipSuccess)
    k_fill<<<dim3(8), dim3(256), 0, stream>>>(out, 4000.0f + (float)(int)e3);
}

// Round 6
// 309.836 us; speedup vs baseline: 1.1297x; 1.1297x over previous
//
#include <hip/hip_runtime.h>

#define B_ 16
#define N_ 16384
#define S_ 4096
#define K_ 16
#define TS 32
#define DOUT 128

typedef __bf16 bf16;
typedef __attribute__((ext_vector_type(8))) __bf16 bf16x8;
typedef __attribute__((ext_vector_type(4))) float f32x4;

__device__ __forceinline__ float lo_bf(unsigned u) {
  union { unsigned i; float f; } c; c.i = u << 16; return c.f;
}
__device__ __forceinline__ float hi_bf(unsigned u) {
  union { unsigned i; float f; } c; c.i = u & 0xffff0000u; return c.f;
}
__device__ __forceinline__ unsigned pack2(float a, float b) {
  unsigned short ua = __builtin_bit_cast(unsigned short, (bf16)a);
  unsigned short ub = __builtin_bit_cast(unsigned short, (bf16)b);
  return (unsigned)ua | ((unsigned)ub << 16);
}
__device__ __forceinline__ void unpack8(uint4 q, float* o) {
  o[0] = lo_bf(q.x); o[1] = hi_bf(q.x);
  o[2] = lo_bf(q.y); o[3] = hi_bf(q.y);
  o[4] = lo_bf(q.z); o[5] = hi_bf(q.z);
  o[6] = lo_bf(q.w); o[7] = hi_bf(q.w);
}

template <int NCH>
__device__ __forceinline__ void ln_leaky(const float* h, const float* g, const float* e, float* o) {
  float m = 0.f;
#pragma unroll
  for (int j = 0; j < NCH; ++j) m += h[j];
  m *= (1.0f / NCH);
  float v = 0.f;
#pragma unroll
  for (int j = 0; j < NCH; ++j) { float d = h[j] - m; v += d * d; }
  v *= (1.0f / NCH);
  float inv = rsqrtf(v + 1e-5f);
#pragma unroll
  for (int j = 0; j < NCH; ++j) {
    float t = (h[j] - m) * inv * g[j] + e[j];
    o[j] = t < 0.f ? 0.2f * t : t;
  }
}

__global__ void k_fill(float* out, float v) {
  out[blockIdx.x * 256 + threadIdx.x] = v;
}

// points [B,64,N] f32 -> ptT [B,N,64] bf16. 8x8 register micro-tile per thread:
// loads and stores both fully coalesced (128B contiguous runs per 8 lanes).
__global__ __launch_bounds__(256) void k_transpose(const float* __restrict__ pts,
                                                   bf16* __restrict__ pt) {
  int b = blockIdx.y;
  int n0 = blockIdx.x * 256;
  int tc = threadIdx.x & 7;   // channel octet selector
  int tn = threadIdx.x >> 3;  // point octet (0..31)
  const float* src = pts + (size_t)b * 64 * N_ + (size_t)(tc * 8) * N_ + n0 + tn * 8;
  float4 row[8][2];
#pragma unroll
  for (int i = 0; i < 8; ++i) {
    row[i][0] = *(const float4*)(src + (size_t)i * N_);
    row[i][1] = *(const float4*)(src + (size_t)i * N_ + 4);
  }
  bf16* dst = pt + ((size_t)b * N_ + n0 + tn * 8) * 64 + tc * 8;
#pragma unroll
  for (int j = 0; j < 8; ++j) {
    float v[8];
#pragma unroll
    for (int i = 0; i < 8; ++i) {
      float4 q = row[i][j >> 2];
      v[i] = ((j & 3) == 0) ? q.x : ((j & 3) == 1) ? q.y : ((j & 3) == 2) ? q.z : q.w;
    }
    *(uint4*)(dst + (size_t)j * 64) = make_uint4(
        pack2(v[0], v[1]), pack2(v[2], v[3]), pack2(v[4], v[5]), pack2(v[6], v[7]));
  }
}

// wl [1072,128] f32 -> wl_t [128,1088] bf16 with rows 1072..1087 zeroed.
__global__ void k_wlt(const float* __restrict__ wl, bf16* __restrict__ wlt) {
  int j = blockIdx.x;
  for (int r = threadIdx.x; r < 1088; r += 256) {
    bf16 v = (bf16)0.0f;
    if (r < 1072) v = (bf16)wl[(size_t)r * 128 + j];
    wlt[(size_t)j * 1088 + r] = v;
  }
}

__global__ __launch_bounds__(256) void k_main(
    const float* __restrict__ xyz, const float* __restrict__ nxyz,
    const int* __restrict__ nnidx,
    const float* __restrict__ pts, const float* __restrict__ wl,
    const bf16* __restrict__ ptT, const bf16* __restrict__ wlT,
    const float* __restrict__ w0p, const float* __restrict__ b0p,
    const float* __restrict__ g0p, const float* __restrict__ be0p,
    const float* __restrict__ w1p, const float* __restrict__ b1p,
    const float* __restrict__ g1p, const float* __restrict__ be1p,
    const float* __restrict__ w2p, const float* __restrict__ b2p,
    const float* __restrict__ g2p, const float* __restrict__ be2p,
    const float* __restrict__ blp, const float* __restrict__ glp,
    const float* __restrict__ belp, float* __restrict__ out, int use_ws) {
  __shared__ float nx[3][TS];
  __shared__ int idxs[TS * K_];
  // w_s bf16[32][264] (16896B) aliased by out_s float[32][132] (16896B) in epilogue
  __shared__ __align__(16) unsigned char poolB[TS * 264 * 2];
  __shared__ __align__(16) bf16 gxn_s[TS][K_][4];
  __shared__ __align__(16) bf16 feat_s[TS][136];   // [s][k*8+c], +8 pad
  __shared__ __align__(16) bf16 aggA[TS][136];     // [s][c*16+m], +8 pad
  __shared__ __align__(16) bf16 wlB[128][136];     // full wl chunk, +8 pad
  __shared__ float ln_m[TS], ln_i[TS];

  const int tid = threadIdx.x;
  const int b = blockIdx.y;
  const int s0 = blockIdx.x * TS;
  bf16* w_s = (bf16*)poolB;  // [s*264 + k*16 + m]

  // ---- phase 0: idx + new_xyz tile ----
  if (tid < 96) {
    int c = tid >> 5, j = tid & 31;
    nx[c][j] = nxyz[((size_t)b * 3 + c) * S_ + s0 + j];
  }
  {
    size_t base = ((size_t)b * S_ + s0) * K_;
    idxs[tid] = nnidx[base + tid];
    idxs[tid + 256] = nnidx[base + tid + 256];
  }
  __syncthreads();

  // ---- phase 1: WeightNet, 2 neighbors per thread ----
  {
    int p0 = tid * 2;
    int s = p0 >> 4;
    int k0 = p0 & 15;
    int na = idxs[p0], nb2 = idxs[p0 + 1];
    float xa[3], xb[3];
#pragma unroll
    for (int c = 0; c < 3; ++c) {
      float nv = nx[c][s];
      xa[c] = xyz[((size_t)b * 3 + c) * N_ + na] - nv;
      xb[c] = xyz[((size_t)b * 3 + c) * N_ + nb2] - nv;
    }
    float ya[8], yb[8];
    {
      float h0[8], h1[8];
#pragma unroll
      for (int j = 0; j < 8; ++j) {
        h0[j] = b0p[j] + xa[0] * w0p[j] + xa[1] * w0p[8 + j] + xa[2] * w0p[16 + j];
        h1[j] = b0p[j] + xb[0] * w0p[j] + xb[1] * w0p[8 + j] + xb[2] * w0p[16 + j];
      }
      ln_leaky<8>(h0, g0p, be0p, ya);
      ln_leaky<8>(h1, g0p, be0p, yb);
    }
    {
      float h0[8], h1[8];
#pragma unroll
      for (int j = 0; j < 8; ++j) { h0[j] = b1p[j]; h1[j] = b1p[j]; }
#pragma unroll
      for (int i = 0; i < 8; ++i) {
#pragma unroll
        for (int j = 0; j < 8; ++j) {
          float w = w1p[i * 8 + j];
          h0[j] += ya[i] * w; h1[j] += yb[i] * w;
        }
      }
      ln_leaky<8>(h0, g1p, be1p, ya);
      ln_leaky<8>(h1, g1p, be1p, yb);
    }
    {
      float h0[16], h1[16];
#pragma unroll
      for (int j = 0; j < 16; ++j) { h0[j] = b2p[j]; h1[j] = b2p[j]; }
#pragma unroll
      for (int i = 0; i < 8; ++i) {
#pragma unroll
        for (int j = 0; j < 16; ++j) {
          float w = w2p[i * 16 + j];
          h0[j] += ya[i] * w; h1[j] += yb[i] * w;
        }
      }
      float z0[16], z1[16];
      ln_leaky<16>(h0, g2p, be2p, z0);
      ln_leaky<16>(h1, g2p, be2p, z1);
      bf16* r0 = w_s + s * 264 + k0 * 16;
      bf16* r1 = r0 + 16;
#pragma unroll
      for (int j = 0; j < 16; j += 2) {
        *(unsigned*)(r0 + j) = pack2(z0[j], z0[j + 1]);
        *(unsigned*)(r1 + j) = pack2(z1[j], z1[j + 1]);
      }
    }
    *(unsigned*)&gxn_s[s][k0][0] = pack2(xa[0], xa[1]);
    *(unsigned*)&gxn_s[s][k0][2] = pack2(xa[2], 0.0f);
    *(unsigned*)&gxn_s[s][k0 + 1][0] = pack2(xb[0], xb[1]);
    *(unsigned*)&gxn_s[s][k0 + 1][2] = pack2(xb[2], 0.0f);
  }

  // ---- MFMA setup ----
  const int lane = tid & 63;
  const int wv = tid >> 6;
  const int rt = wv & 1;
  const int cw = wv >> 1;
  const int quad = lane >> 4;
  const int l16 = lane & 15;
  f32x4 a00 = {0.f, 0.f, 0.f, 0.f};
  f32x4 a01 = a00, a10 = a00, a11 = a00;

  const bf16* ptB = ptT + (size_t)b * N_ * 64;

  // prefetch helper state
  uint4 pf0, pf1;
  auto prefetch = [&](int nc) {
    if (nc < 8) {
      int n = idxs[tid];
      int n2 = idxs[tid + 256];
      if (use_ws) {
        pf0 = *(const uint4*)(ptB + (size_t)n * 64 + nc * 8);
        pf1 = *(const uint4*)(ptB + (size_t)n2 * 64 + nc * 8);
      } else {
        const float* base = pts + ((size_t)b * 64 + nc * 8) * N_;
        unsigned u[4];
#pragma unroll
        for (int c = 0; c < 4; ++c)
          u[c] = pack2(base[(size_t)(2 * c) * N_ + n], base[(size_t)(2 * c + 1) * N_ + n]);
        pf0 = make_uint4(u[0], u[1], u[2], u[3]);
#pragma unroll
        for (int c = 0; c < 4; ++c)
          u[c] = pack2(base[(size_t)(2 * c) * N_ + n2], base[(size_t)(2 * c + 1) * N_ + n2]);
        pf1 = make_uint4(u[0], u[1], u[2], u[3]);
      }
    } else {
      int s = tid >> 4, k = tid & 15;
      pf0 = make_uint4(*(const unsigned*)&gxn_s[s][k][0],
                       *(const unsigned*)&gxn_s[s][k][2], 0u, 0u);
      int p2 = tid + 256; s = p2 >> 4; k = p2 & 15;
      pf1 = make_uint4(*(const unsigned*)&gxn_s[s][k][0],
                       *(const unsigned*)&gxn_s[s][k][2], 0u, 0u);
    }
  };
  prefetch(0);

  for (int ch = 0; ch < 9; ++ch) {
    const int kw = (ch < 8) ? 128 : 64;
    __syncthreads();  // (A) prev mfma done with wlB/aggA; prev agg done with feat_s
    // stage feat from prefetched regs
    {
      int s = tid >> 4, k = tid & 15;
      *(uint4*)&feat_s[s][k * 8] = pf0;
      int p2 = tid + 256; s = p2 >> 4; k = p2 & 15;
      *(uint4*)&feat_s[s][k * 8] = pf1;
    }
    // stage full wl chunk: 128 rows x kw cols
    {
      int j = tid >> 1, sg = tid & 1;
      int per = kw >> 1;  // 64 or 32
      const bf16* src = wlT + (size_t)j * 1088 + ch * 128 + sg * per;
      bf16* dst = &wlB[j][sg * per];
#pragma unroll
      for (int i = 0; i < 64; i += 8)
        if (i < per) *(uint4*)(dst + i) = *(const uint4*)(src + i);
    }
    __syncthreads();  // (B)
    if (ch < 8) prefetch(ch + 1);  // hide gather latency behind agg+mfma
    // agg: aggA[s][c*16+m] = sum_k feat[s,k,c] * w[s,k,m]
    {
      int s = tid >> 3, mp = tid & 7;
      float acc0[8], acc1[8];
#pragma unroll
      for (int c = 0; c < 8; ++c) { acc0[c] = 0.f; acc1[c] = 0.f; }
      const bf16* wrow = w_s + s * 264 + 2 * mp;
      const bf16* frow = &feat_s[s][0];
#pragma unroll
      for (int k = 0; k < 16; ++k) {
        unsigned wp = *(const unsigned*)(wrow + k * 16);
        float wf0 = lo_bf(wp), wf1 = hi_bf(wp);
        float f[8];
        unpack8(*(const uint4*)(frow + k * 8), f);
#pragma unroll
        for (int c = 0; c < 8; ++c) { acc0[c] += f[c] * wf0; acc1[c] += f[c] * wf1; }
      }
      bf16* arow = &aggA[s][0];
#pragma unroll
      for (int c = 0; c < 8; ++c)
        *(unsigned*)(arow + c * 16 + 2 * mp) = pack2(acc0[c], acc1[c]);
    }
    __syncthreads();  // (C)
    // MFMA: all 4 col-tiles in one phase
    {
      const int nkk = kw >> 5;
      const bf16* arow = &aggA[rt * 16 + l16][quad * 8];
      const bf16* b0r = &wlB[(2 * cw + 0) * 16 + l16][quad * 8];
      const bf16* b1r = &wlB[(2 * cw + 1) * 16 + l16][quad * 8];
      const bf16* b2r = &wlB[64 + (2 * cw + 0) * 16 + l16][quad * 8];
      const bf16* b3r = &wlB[64 + (2 * cw + 1) * 16 + l16][quad * 8];
      for (int kk = 0; kk < nkk; ++kk) {
        bf16x8 af = *(const bf16x8*)(arow + kk * 32);
        bf16x8 bf0 = *(const bf16x8*)(b0r + kk * 32);
        bf16x8 bf1 = *(const bf16x8*)(b1r + kk * 32);
        bf16x8 bf2 = *(const bf16x8*)(b2r + kk * 32);
        bf16x8 bf3 = *(const bf16x8*)(b3r + kk * 32);
        a00 = __builtin_amdgcn_mfma_f32_16x16x32_bf16(af, bf0, a00, 0, 0, 0);
        a01 = __builtin_amdgcn_mfma_f32_16x16x32_bf16(af, bf1, a01, 0, 0, 0);
        a10 = __builtin_amdgcn_mfma_f32_16x16x32_bf16(af, bf2, a10, 0, 0, 0);
        a11 = __builtin_amdgcn_mfma_f32_16x16x32_bf16(af, bf3, a11, 0, 0, 0);
      }
    }
  }

  __syncthreads();
  // ---- epilogue: +bl, LN over 128, *gl+bel, leaky, transposed f32 store ----
  float* out_s = (float*)poolB;  // [32][132] padded; aliases w_s (dead now)
  {
    int row = rt * 16 + quad * 4;
    int c0 = (2 * cw + 0) * 16 + l16;
    int c1 = (2 * cw + 1) * 16 + l16;
    int c2 = 64 + c0;
    int c3 = 64 + c1;
    float bl0 = blp[c0], bl1 = blp[c1], bl2 = blp[c2], bl3 = blp[c3];
#pragma unroll
    for (int r = 0; r < 4; ++r) {
      out_s[(row + r) * 132 + c0] = a00[r] + bl0;
      out_s[(row + r) * 132 + c1] = a01[r] + bl1;
      out_s[(row + r) * 132 + c2] = a10[r] + bl2;
      out_s[(row + r) * 132 + c3] = a11[r] + bl3;
    }
  }
  __syncthreads();
  // LN stats: 8 threads per row, shfl-xor reduce (conflict-free reads)
  {
    int r = tid >> 3, g = tid & 7;
    const float* rowp = out_s + r * 132;
    float s1 = 0.f;
#pragma unroll
    for (int i = 0; i < 16; ++i) s1 += rowp[g + 8 * i];
    s1 += __shfl_xor(s1, 1);
    s1 += __shfl_xor(s1, 2);
    s1 += __shfl_xor(s1, 4);
    float m = s1 * (1.0f / 128.0f);
    float s2 = 0.f;
#pragma unroll
    for (int i = 0; i < 16; ++i) { float d = rowp[g + 8 * i] - m; s2 += d * d; }
    s2 += __shfl_xor(s2, 1);
    s2 += __shfl_xor(s2, 2);
    s2 += __shfl_xor(s2, 4);
    if (g == 0) {
      ln_m[r] = m;
      ln_i[r] = rsqrtf(s2 * (1.0f / 128.0f) + 1e-5f);
    }
  }
  __syncthreads();
  {
    int d = tid >> 1, sh = tid & 1;
    float gld = glp[d], beld = belp[d];
    float vals[16];
#pragma unroll
    for (int j = 0; j < 16; ++j) {
      int r = sh * 16 + j;
      float v = (out_s[r * 132 + d] - ln_m[r]) * ln_i[r] * gld + beld;
      vals[j] = v < 0.f ? 0.2f * v : v;
    }
    float* op = out + ((size_t)b * DOUT + d) * S_ + s0 + sh * 16;
#pragma unroll
    for (int i = 0; i < 4; ++i)
      *(float4*)(op + 4 * i) =
          make_float4(vals[4 * i], vals[4 * i + 1], vals[4 * i + 2], vals[4 * i + 3]);
  }
}

extern "C" void kernel_launch(void* const* d_in, const int* in_sizes, int n_in,
                              void* d_out, int out_size, void* d_ws, size_t ws_size,
                              hipStream_t stream) {
  const float* xyz  = (const float*)d_in[0];
  const float* pts  = (const float*)d_in[1];
  const float* nxyz = (const float*)d_in[2];
  const int* nnidx  = (const int*)d_in[3];
  const float* w0p  = (const float*)d_in[4];
  const float* b0p  = (const float*)d_in[5];
  const float* g0p  = (const float*)d_in[6];
  const float* be0p = (const float*)d_in[7];
  const float* w1p  = (const float*)d_in[8];
  const float* b1p  = (const float*)d_in[9];
  const float* g1p  = (const float*)d_in[10];
  const float* be1p = (const float*)d_in[11];
  const float* w2p  = (const float*)d_in[12];
  const float* b2p  = (const float*)d_in[13];
  const float* g2p  = (const float*)d_in[14];
  const float* be2p = (const float*)d_in[15];
  const float* wlp  = (const float*)d_in[16];
  const float* blp  = (const float*)d_in[17];
  const float* glp  = (const float*)d_in[18];
  const float* belp = (const float*)d_in[19];
  float* out = (float*)d_out;

  const size_t PTT_BYTES = (size_t)B_ * N_ * 64 * 2;
  const size_t WLT_BYTES = (size_t)128 * 1088 * 2;
  const int use_ws = (ws_size >= PTT_BYTES + WLT_BYTES) ? 1 : 0;
  bf16* ptT = (bf16*)d_ws;
  bf16* wlT = (bf16*)((char*)d_ws + PTT_BYTES);

  (void)hipGetLastError();

  hipError_t e1 = hipSuccess, e2 = hipSuccess;
  if (use_ws) {
    k_transpose<<<dim3(N_ / 256, B_), dim3(256), 0, stream>>>(pts, ptT);
    e1 = hipGetLastError();
    k_wlt<<<dim3(128), dim3(256), 0, stream>>>(wlp, wlT);
    e2 = hipGetLastError();
  }
  k_main<<<dim3(S_ / TS, B_), dim3(256), 0, stream>>>(
      xyz, nxyz, nnidx, pts, wlp, ptT, wlT,
      w0p, b0p, g0p, be0p, w1p, b1p, g1p, be1p,
      w2p, b2p, g2p, be2p, blp, glp, belp, out, use_ws);
  hipError_t e3 = hipGetLastError();

  if (e1 != hipSuccess)
    k_fill<<<dim3(8), dim3(256), 0, stream>>>(out, 2000.0f + (float)(int)e1);
  if (e2 != hipSuccess)
    k_fill<<<dim3(8), dim3(256), 0, stream>>>(out, 3000.0f + (float)(int)e2);
  if (e3 != hipSuccess)
    k_fill<<<dim3(8), dim3(256), 0, stream>>>(out, 4000.0f + (float)(int)e3);
}

// Round 7
// 265.013 us; speedup vs baseline: 1.3207x; 1.1691x over previous
//
#include <hip/hip_runtime.h>

#define B_ 16
#define N_ 16384
#define S_ 4096
#define K_ 16
#define TS 32
#define DOUT 128

typedef __bf16 bf16;
typedef __attribute__((ext_vector_type(8))) __bf16 bf16x8;
typedef __attribute__((ext_vector_type(4))) float f32x4;

__device__ __forceinline__ unsigned pack2(float a, float b) {
  unsigned short ua = __builtin_bit_cast(unsigned short, (bf16)a);
  unsigned short ub = __builtin_bit_cast(unsigned short, (bf16)b);
  return (unsigned)ua | ((unsigned)ub << 16);
}

template <int NCH>
__device__ __forceinline__ void ln_leaky(const float* h, const float* g, const float* e, float* o) {
  float m = 0.f;
#pragma unroll
  for (int j = 0; j < NCH; ++j) m += h[j];
  m *= (1.0f / NCH);
  float v = 0.f;
#pragma unroll
  for (int j = 0; j < NCH; ++j) { float d = h[j] - m; v += d * d; }
  v *= (1.0f / NCH);
  float inv = rsqrtf(v + 1e-5f);
#pragma unroll
  for (int j = 0; j < NCH; ++j) {
    float t = (h[j] - m) * inv * g[j] + e[j];
    o[j] = t < 0.f ? 0.2f * t : t;
  }
}

__global__ void k_fill(float* out, float v) {
  out[blockIdx.x * 256 + threadIdx.x] = v;
}

// points [B,64,N] f32 -> ptT [B,N,64] bf16 (unchanged from r6).
__global__ __launch_bounds__(256) void k_transpose(const float* __restrict__ pts,
                                                   bf16* __restrict__ pt) {
  int b = blockIdx.y;
  int n0 = blockIdx.x * 256;
  int tc = threadIdx.x & 7;
  int tn = threadIdx.x >> 3;
  const float* src = pts + (size_t)b * 64 * N_ + (size_t)(tc * 8) * N_ + n0 + tn * 8;
  float4 row[8][2];
#pragma unroll
  for (int i = 0; i < 8; ++i) {
    row[i][0] = *(const float4*)(src + (size_t)i * N_);
    row[i][1] = *(const float4*)(src + (size_t)i * N_ + 4);
  }
  bf16* dst = pt + ((size_t)b * N_ + n0 + tn * 8) * 64 + tc * 8;
#pragma unroll
  for (int j = 0; j < 8; ++j) {
    float v[8];
#pragma unroll
    for (int i = 0; i < 8; ++i) {
      float4 q = row[i][j >> 2];
      v[i] = ((j & 3) == 0) ? q.x : ((j & 3) == 1) ? q.y : ((j & 3) == 2) ? q.z : q.w;
    }
    *(uint4*)(dst + (size_t)j * 64) = make_uint4(
        pack2(v[0], v[1]), pack2(v[2], v[3]), pack2(v[4], v[5]), pack2(v[6], v[7]));
  }
}

// wl [1072,128] f32 -> wlF: B-fragment-order bf16 so a wave's MFMA B-frag is one
// coalesced 1KB load. Element for (tile t, kkg, lane L, j):
//   wl_k = kkg*32 + (L>>4)*8 + j   (zero for wl_k >= 1072)
//   n    = t*16 + (L&15)
// wlF short index = ((t*34 + kkg)*64 + L)*8 + j.  Size 8*34*64*8 = 139264 shorts.
__global__ void k_wlf(const float* __restrict__ wl, bf16* __restrict__ wlF) {
  int blk = blockIdx.x;            // t*34 + kkg
  int kkg = blk % 34;
  int t = blk / 34;
  int tid = threadIdx.x;
  int L = tid >> 2, jp = (tid & 3) * 2;
  int k = kkg * 32 + ((L >> 4) << 3) + jp;
  int n = t * 16 + (L & 15);
  float v0 = (k < 1072) ? wl[(size_t)k * 128 + n] : 0.f;
  float v1 = (k + 1 < 1072) ? wl[(size_t)(k + 1) * 128 + n] : 0.f;
  ((unsigned*)wlF)[(size_t)blk * 256 + tid] = pack2(v0, v1);
}

__global__ __launch_bounds__(256, 4) void k_main(
    const float* __restrict__ xyz, const float* __restrict__ nxyz,
    const int* __restrict__ nnidx,
    const bf16* __restrict__ ptT, const bf16* __restrict__ wlF,
    const float* __restrict__ w0p, const float* __restrict__ b0p,
    const float* __restrict__ g0p, const float* __restrict__ be0p,
    const float* __restrict__ w1p, const float* __restrict__ b1p,
    const float* __restrict__ g1p, const float* __restrict__ be1p,
    const float* __restrict__ w2p, const float* __restrict__ b2p,
    const float* __restrict__ g2p, const float* __restrict__ be2p,
    const float* __restrict__ blp, const float* __restrict__ glp,
    const float* __restrict__ belp, float* __restrict__ out) {
  // LDS (35.4 KB total -> 4 blocks/CU):
  __shared__ __align__(16) bf16 w_sT[32 * 264];   // [s][m*16+k], s-stride 264 (pad 8)
  __shared__ __align__(16) bf16 feat2[32 * 144];  // [s][c*16+k], s-stride 144 (pad 16)
  __shared__ __align__(16) bf16 aggA[32 * 136];   // [s][c*16+m], s-stride 136 (pad 8)
  __shared__ float nx[3][TS];
  __shared__ float ln_m[TS], ln_i[TS];

  const int tid = threadIdx.x;
  const int b = blockIdx.y;
  const int s0 = blockIdx.x * TS;
  const size_t ibase = ((size_t)b * S_ + s0) * K_;

  if (tid < 96) {
    int c = tid >> 5, j = tid & 31;
    nx[c][j] = nxyz[((size_t)b * 3 + c) * S_ + s0 + j];
  }
  // gather-phase indices (this thread's two points), register-resident
  const int ig0 = nnidx[ibase + tid];
  const int ig1 = nnidx[ibase + tid + 256];
  // weightnet-phase indices (points 2*tid, 2*tid+1)
  const int iw0 = nnidx[ibase + 2 * tid];
  const int iw1 = nnidx[ibase + 2 * tid + 1];
  __syncthreads();

  // ---- WeightNet: points p0=2*tid (s=tid>>3, k0=2*(tid&7)) and p0+1 ----
  float xa[3], xb[3];
  const int ws = tid >> 3;        // s for weightnet outputs
  const int wk = (tid & 7) * 2;   // even k
  {
#pragma unroll
    for (int c = 0; c < 3; ++c) {
      float nv = nx[c][ws];
      xa[c] = xyz[((size_t)b * 3 + c) * N_ + iw0] - nv;
      xb[c] = xyz[((size_t)b * 3 + c) * N_ + iw1] - nv;
    }
    float ya[8], yb[8];
    {
      float h0[8], h1[8];
#pragma unroll
      for (int j = 0; j < 8; ++j) {
        h0[j] = b0p[j] + xa[0] * w0p[j] + xa[1] * w0p[8 + j] + xa[2] * w0p[16 + j];
        h1[j] = b0p[j] + xb[0] * w0p[j] + xb[1] * w0p[8 + j] + xb[2] * w0p[16 + j];
      }
      ln_leaky<8>(h0, g0p, be0p, ya);
      ln_leaky<8>(h1, g0p, be0p, yb);
    }
    {
      float h0[8], h1[8];
#pragma unroll
      for (int j = 0; j < 8; ++j) { h0[j] = b1p[j]; h1[j] = b1p[j]; }
#pragma unroll
      for (int i = 0; i < 8; ++i) {
#pragma unroll
        for (int j = 0; j < 8; ++j) {
          float w = w1p[i * 8 + j];
          h0[j] += ya[i] * w; h1[j] += yb[i] * w;
        }
      }
      ln_leaky<8>(h0, g1p, be1p, ya);
      ln_leaky<8>(h1, g1p, be1p, yb);
    }
    {
      float h0[16], h1[16];
#pragma unroll
      for (int j = 0; j < 16; ++j) { h0[j] = b2p[j]; h1[j] = b2p[j]; }
#pragma unroll
      for (int i = 0; i < 8; ++i) {
#pragma unroll
        for (int j = 0; j < 16; ++j) {
          float w = w2p[i * 16 + j];
          h0[j] += ya[i] * w; h1[j] += yb[i] * w;
        }
      }
      float z0[16], z1[16];
      ln_leaky<16>(h0, g2p, be2p, z0);
      ln_leaky<16>(h1, g2p, be2p, z1);
      // w_sT[s][m*16+k]: pack both k's (wk, wk+1) into one b32 per m
      bf16* wp = w_sT + ws * 264 + wk;
#pragma unroll
      for (int m = 0; m < 16; ++m)
        *(unsigned*)(wp + m * 16) = pack2(z0[m], z1[m]);
    }
  }

  // ---- MFMA wave geometry ----
  const int lane = tid & 63;
  const int wv = tid >> 6;
  const int rt = wv & 1;        // main-GEMM row tile
  const int cw = wv >> 1;       // main-GEMM col pair
  const int l16 = lane & 15;
  const int q = lane >> 4;
  // agg-MFMA lane roles
  const bool adiag = ((((lane >> 5) ^ (lane >> 3)) & 1) == 0);
  const int aoff = ((lane >> 3) & 1) * 144 + (lane & 7) * 16 + (q & 1) * 8;
  const int boff = (lane >> 5) * 264 + l16 * 16 + (q & 1) * 8;
  const int soff = (lane >> 5) * 136 + (q & 1) * 64 + l16;  // + r*16
  f32x4 a00 = {0.f, 0.f, 0.f, 0.f};
  f32x4 a01 = a00, a10 = a00, a11 = a00;
  const f32x4 zc = a00;

  const bf16* ptB = ptT + (size_t)b * N_ * 64;
  const int gs0 = tid >> 4, gk = tid & 15;  // gather slots: s=gs0 / gs0+16, k=gk

  uint4 pf0, pf1;
  pf0 = *(const uint4*)(ptB + (size_t)ig0 * 64);
  pf1 = *(const uint4*)(ptB + (size_t)ig1 * 64);

  for (int ch = 0; ch < 9; ++ch) {
    const int nkk = (ch < 8) ? 4 : 2;
    __syncthreads();  // (A) prev agg done with feat2/w_sT reads; prev main done with aggA
    // stage feat2[s][c*16+k] for this chunk
    if (ch < 8) {
      bf16 t0[8], t1[8];
      *(uint4*)t0 = pf0;
      *(uint4*)t1 = pf1;
      bf16* f0 = feat2 + gs0 * 144 + gk;
      bf16* f1 = feat2 + (gs0 + 16) * 144 + gk;
#pragma unroll
      for (int c = 0; c < 8; ++c) {
        f0[c * 16] = t0[c];
        f1[c * 16] = t1[c];
      }
    } else {
      // gxn channels (3 real + 5 zero), packed pairs (wk, wk+1)
      bf16* fp = feat2 + ws * 144 + wk;
      *(unsigned*)(fp + 0 * 16) = pack2(xa[0], xb[0]);
      *(unsigned*)(fp + 1 * 16) = pack2(xa[1], xb[1]);
      *(unsigned*)(fp + 2 * 16) = pack2(xa[2], xb[2]);
#pragma unroll
      for (int c = 3; c < 8; ++c) *(unsigned*)(fp + c * 16) = 0u;
    }
    __syncthreads();  // (B)
    if (ch < 8) {  // prefetch next chunk's gather
      int nc = ch + 1;
      if (nc < 8) {
        pf0 = *(const uint4*)(ptB + (size_t)ig0 * 64 + nc * 8);
        pf1 = *(const uint4*)(ptB + (size_t)ig1 * 64 + nc * 8);
      }
    }
    // agg via block-diagonal MFMA: 2 s per MFMA, 4 MFMAs per wave
#pragma unroll
    for (int pp = 0; pp < 4; ++pp) {
      int s2 = (wv * 4 + pp) * 2;
      uint4 au = *(const uint4*)(feat2 + s2 * 144 + aoff);
      if (!adiag) au = make_uint4(0u, 0u, 0u, 0u);
      bf16x8 af = __builtin_bit_cast(bf16x8, au);
      bf16x8 bw = *(const bf16x8*)(w_sT + s2 * 264 + boff);
      f32x4 d = __builtin_amdgcn_mfma_f32_16x16x32_bf16(af, bw, zc, 0, 0, 0);
      bf16* cp = aggA + s2 * 136 + soff;
#pragma unroll
      for (int r = 0; r < 4; ++r) cp[r * 16] = (bf16)d[r];
    }
    __syncthreads();  // (C)
    // main GEMM: A from aggA (LDS), B from wlF (global, coalesced 1KB/wave)
    {
      const bf16* arow = aggA + (rt * 16 + l16) * 136 + q * 8;
      const size_t lb = (size_t)lane * 8;
      const size_t kb = (size_t)(ch * 4) * 512;
      const bf16* w0f = wlF + (size_t)(2 * cw + 0) * 17408 + kb + lb;
      const bf16* w1f = wlF + (size_t)(2 * cw + 1) * 17408 + kb + lb;
      const bf16* w2f = wlF + (size_t)(2 * cw + 4) * 17408 + kb + lb;
      const bf16* w3f = wlF + (size_t)(2 * cw + 5) * 17408 + kb + lb;
      for (int kk = 0; kk < nkk; ++kk) {
        bf16x8 af = *(const bf16x8*)(arow + kk * 32);
        bf16x8 bf0 = *(const bf16x8*)(w0f + kk * 512);
        bf16x8 bf1 = *(const bf16x8*)(w1f + kk * 512);
        bf16x8 bf2 = *(const bf16x8*)(w2f + kk * 512);
        bf16x8 bf3 = *(const bf16x8*)(w3f + kk * 512);
        a00 = __builtin_amdgcn_mfma_f32_16x16x32_bf16(af, bf0, a00, 0, 0, 0);
        a01 = __builtin_amdgcn_mfma_f32_16x16x32_bf16(af, bf1, a01, 0, 0, 0);
        a10 = __builtin_amdgcn_mfma_f32_16x16x32_bf16(af, bf2, a10, 0, 0, 0);
        a11 = __builtin_amdgcn_mfma_f32_16x16x32_bf16(af, bf3, a11, 0, 0, 0);
      }
    }
  }

  __syncthreads();
  // ---- epilogue: +bl, LN(128), *gl+bel, leaky, transposed f32 store ----
  float* out_s = (float*)w_sT;  // [32][132]; w_sT dead now
  {
    int row = rt * 16 + q * 4;
    int c0 = (2 * cw + 0) * 16 + l16;
    int c1 = (2 * cw + 1) * 16 + l16;
    int c2 = 64 + c0;
    int c3 = 64 + c1;
    float bl0 = blp[c0], bl1 = blp[c1], bl2 = blp[c2], bl3 = blp[c3];
#pragma unroll
    for (int r = 0; r < 4; ++r) {
      out_s[(row + r) * 132 + c0] = a00[r] + bl0;
      out_s[(row + r) * 132 + c1] = a01[r] + bl1;
      out_s[(row + r) * 132 + c2] = a10[r] + bl2;
      out_s[(row + r) * 132 + c3] = a11[r] + bl3;
    }
  }
  __syncthreads();
  {
    int r = tid >> 3, g = tid & 7;
    const float* rowp = out_s + r * 132;
    float s1 = 0.f;
#pragma unroll
    for (int i = 0; i < 16; ++i) s1 += rowp[g + 8 * i];
    s1 += __shfl_xor(s1, 1);
    s1 += __shfl_xor(s1, 2);
    s1 += __shfl_xor(s1, 4);
    float m = s1 * (1.0f / 128.0f);
    float s2 = 0.f;
#pragma unroll
    for (int i = 0; i < 16; ++i) { float d = rowp[g + 8 * i] - m; s2 += d * d; }
    s2 += __shfl_xor(s2, 1);
    s2 += __shfl_xor(s2, 2);
    s2 += __shfl_xor(s2, 4);
    if (g == 0) {
      ln_m[r] = m;
      ln_i[r] = rsqrtf(s2 * (1.0f / 128.0f) + 1e-5f);
    }
  }
  __syncthreads();
  {
    int d = tid >> 1, sh = tid & 1;
    float gld = glp[d], beld = belp[d];
    float vals[16];
#pragma unroll
    for (int j = 0; j < 16; ++j) {
      int r = sh * 16 + j;
      float v = (out_s[r * 132 + d] - ln_m[r]) * ln_i[r] * gld + beld;
      vals[j] = v < 0.f ? 0.2f * v : v;
    }
    float* op = out + ((size_t)b * DOUT + d) * S_ + s0 + sh * 16;
#pragma unroll
    for (int i = 0; i < 4; ++i)
      *(float4*)(op + 4 * i) =
          make_float4(vals[4 * i], vals[4 * i + 1], vals[4 * i + 2], vals[4 * i + 3]);
  }
}

extern "C" void kernel_launch(void* const* d_in, const int* in_sizes, int n_in,
                              void* d_out, int out_size, void* d_ws, size_t ws_size,
                              hipStream_t stream) {
  const float* xyz  = (const float*)d_in[0];
  const float* pts  = (const float*)d_in[1];
  const float* nxyz = (const float*)d_in[2];
  const int* nnidx  = (const int*)d_in[3];
  const float* w0p  = (const float*)d_in[4];
  const float* b0p  = (const float*)d_in[5];
  const float* g0p  = (const float*)d_in[6];
  const float* be0p = (const float*)d_in[7];
  const float* w1p  = (const float*)d_in[8];
  const float* b1p  = (const float*)d_in[9];
  const float* g1p  = (const float*)d_in[10];
  const float* be1p = (const float*)d_in[11];
  const float* w2p  = (const float*)d_in[12];
  const float* b2p  = (const float*)d_in[13];
  const float* g2p  = (const float*)d_in[14];
  const float* be2p = (const float*)d_in[15];
  const float* wlp  = (const float*)d_in[16];
  const float* blp  = (const float*)d_in[17];
  const float* glp  = (const float*)d_in[18];
  const float* belp = (const float*)d_in[19];
  float* out = (float*)d_out;

  const size_t PTT_BYTES = (size_t)B_ * N_ * 64 * 2;       // 33.55 MB
  const size_t WLF_BYTES = (size_t)8 * 34 * 64 * 8 * 2;    // 0.27 MB
  bf16* ptT = (bf16*)d_ws;
  bf16* wlF = (bf16*)((char*)d_ws + PTT_BYTES);

  (void)hipGetLastError();

  if (ws_size < PTT_BYTES + WLF_BYTES) {
    k_fill<<<dim3(8), dim3(256), 0, stream>>>(out, 5000.0f);
    return;
  }

  k_transpose<<<dim3(N_ / 256, B_), dim3(256), 0, stream>>>(pts, ptT);
  hipError_t e1 = hipGetLastError();
  k_wlf<<<dim3(8 * 34), dim3(256), 0, stream>>>(wlp, wlF);
  hipError_t e2 = hipGetLastError();
  k_main<<<dim3(S_ / TS, B_), dim3(256), 0, stream>>>(
      xyz, nxyz, nnidx, ptT, wlF,
      w0p, b0p, g0p, be0p, w1p, b1p, g1p, be1p,
      w2p, b2p, g2p, be2p, blp, glp, belp, out);
  hipError_t e3 = hipGetLastError();

  if (e1 != hipSuccess)
    k_fill<<<dim3(8), dim3(256), 0, stream>>>(out, 2000.0f + (float)(int)e1);
  if (e2 != hipSuccess)
    k_fill<<<dim3(8), dim3(256), 0, stream>>>(out, 3000.0f + (float)(int)e2);
  if (e3 != hipSuccess)
    k_fill<<<dim3(8), dim3(256), 0, stream>>>(out, 4000.0f + (float)(int)e3);
}